// Round 2
// baseline (11285.960 us; speedup 1.0000x reference)
//
#include <hip/hip_runtime.h>
#include <hip/hip_bf16.h>

#define NNODE 50000
#define NEDGE 500000
#define FIN   128
#define HID   64
#define FOUT  64
#define SZ    4096
#define NITEMS 4096

// ---------------------------------------------------------------------------
// Generic tiled GEMM: C[M,Nn] = act(A[M,K] @ B[K,Nn] (+bias) (+C))
// MODEA: 0 = A fp32 [M,K], 1 = A is concat(Adj [M,4096], fake [M,64]) fp32
// ---------------------------------------------------------------------------
template<int MODEA, int DORELU, int DOSIG, int DOACC, int DOBIAS>
__global__ __launch_bounds__(256)
void gemm_k(const float* __restrict__ Aptr, const float* __restrict__ Adj,
            const float* __restrict__ B, const float* __restrict__ bias,
            float* __restrict__ Cptr, int M, int Nn, int K)
{
    const int BK = 16;
    __shared__ float As[16][68];   // [kk][m], padded
    __shared__ float Bs[16][68];   // [kk][n], padded
    const int tid = threadIdx.x;
    const int tr = tid >> 4, tc = tid & 15;
    const int row0 = blockIdx.y * 64;
    const int col0 = blockIdx.x * 64;
    float acc[4][4];
#pragma unroll
    for (int i = 0; i < 4; ++i)
#pragma unroll
        for (int j = 0; j < 4; ++j) acc[i][j] = 0.f;

    for (int k0 = 0; k0 < K; k0 += BK) {
        // A tile: 64 rows x 16 k  (1024 elems, 4/thread)
#pragma unroll
        for (int l = 0; l < 4; ++l) {
            int i = tid + l * 256;
            int m = i >> 4, kk = i & 15;
            int gm = row0 + m, gk = k0 + kk;
            float v = 0.f;
            if (gm < M && gk < K) {
                if (MODEA == 0) v = Aptr[(size_t)gm * K + gk];
                else v = (gk < NITEMS) ? Adj[(size_t)gm * NITEMS + gk]
                                       : Aptr[(size_t)gm * FOUT + (gk - NITEMS)];
            }
            As[kk][m] = v;
        }
        // B tile: 16 k x 64 cols
#pragma unroll
        for (int l = 0; l < 4; ++l) {
            int i = tid + l * 256;
            int kk = i >> 6, n = i & 63;
            int gk = k0 + kk, gn = col0 + n;
            float v = 0.f;
            if (gk < K && gn < Nn) v = B[(size_t)gk * Nn + gn];
            Bs[kk][n] = v;
        }
        __syncthreads();
#pragma unroll
        for (int kk = 0; kk < BK; ++kk) {
            float a[4], b[4];
#pragma unroll
            for (int i = 0; i < 4; ++i) a[i] = As[kk][tr * 4 + i];
#pragma unroll
            for (int j = 0; j < 4; ++j) b[j] = Bs[kk][tc * 4 + j];
#pragma unroll
            for (int i = 0; i < 4; ++i)
#pragma unroll
                for (int j = 0; j < 4; ++j)
                    acc[i][j] = fmaf(a[i], b[j], acc[i][j]);
        }
        __syncthreads();
    }

#pragma unroll
    for (int i = 0; i < 4; ++i) {
        int gm = row0 + tr * 4 + i;
        if (gm >= M) continue;
#pragma unroll
        for (int j = 0; j < 4; ++j) {
            int gn = col0 + tc * 4 + j;
            if (gn >= Nn) continue;
            float v = acc[i][j];
            if (DOBIAS) v += bias[gn];
            size_t off = (size_t)gm * Nn + gn;
            if (DOACC) v += Cptr[off];
            if (DORELU) v = fmaxf(v, 0.f);
            if (DOSIG)  v = 1.f / (1.f + expf(-v));
            Cptr[off] = v;
        }
    }
}

// ---------------------------------------------------------------------------
// segment_max via atomicMax on int bits. Valid because pooled = relu(..) >= 0,
// and agg is 0-initialized (which also implements the isneginf->0 rule).
// ---------------------------------------------------------------------------
template<int F>
__global__ __launch_bounds__(256)
void scatter_max_k(const float* __restrict__ pooled, const int* __restrict__ sidx,
                   const int* __restrict__ didx, float* __restrict__ agg)
{
    const int CH = F / 4;
    long long tid = (long long)blockIdx.x * 256 + threadIdx.x;
    int e = (int)(tid / CH);
    if (e >= NEDGE) return;
    int c = ((int)(tid % CH)) * 4;
    int s = sidx[e], d = didx[e];
    const float4 v = *reinterpret_cast<const float4*>(pooled + (size_t)s * F + c);
    int* a = reinterpret_cast<int*>(agg + (size_t)d * F + c);
    atomicMax(a + 0, __float_as_int(v.x));
    atomicMax(a + 1, __float_as_int(v.y));
    atomicMax(a + 2, __float_as_int(v.z));
    atomicMax(a + 3, __float_as_int(v.w));
}

// ---------------------------------------------------------------------------
// fake = sr[t] * L1norm(mirna)[left+r] + nr[t] * noise[left+r]; one wave/row
// ---------------------------------------------------------------------------
__global__ __launch_bounds__(64)
void fake_k(const float* __restrict__ mirna, const float* __restrict__ noise,
            const int* __restrict__ t_p, const int* __restrict__ left_p,
            float* __restrict__ fakef, float* __restrict__ fake_out)
{
    int r = blockIdx.x;
    int c = threadIdx.x;
    int t = *t_p;
    int left = *left_p;
    int row = left + r;
    float x = mirna[(size_t)row * FOUT + c];
    float s = fabsf(x);
#pragma unroll
    for (int off = 32; off > 0; off >>= 1) s += __shfl_down(s, off);
    s = __shfl(s, 0);
    float ab = 1.f;
    for (int i = 0; i <= t; ++i) {
        float beta = 1e-4f + (0.02f - 1e-4f) * ((float)i / 99.f);
        ab *= (1.f - beta);
    }
    float srate = sqrtf(ab);
    float nrate = sqrtf(1.f - ab);
    float y = x / fmaxf(s, 1e-12f);
    float v = srate * y + nrate * noise[(size_t)row * FOUT + c];
    fakef[(size_t)r * FOUT + c] = v;
    fake_out[(size_t)r * FOUT + c] = v;
}

// ---------------------------------------------------------------------------
extern "C" void kernel_launch(void* const* d_in, const int* in_sizes, int n_in,
                              void* d_out, int out_size, void* d_ws, size_t ws_size,
                              hipStream_t stream)
{
    const float* h0[3]     = {(const float*)d_in[0],  (const float*)d_in[1],  (const float*)d_in[2]};
    const float* Wpool[3]  = {(const float*)d_in[3],  (const float*)d_in[8],  (const float*)d_in[13]};
    const float* bpool[3]  = {(const float*)d_in[4],  (const float*)d_in[9],  (const float*)d_in[14]};
    const float* Wself[3]  = {(const float*)d_in[5],  (const float*)d_in[10], (const float*)d_in[15]};
    const float* bself[3]  = {(const float*)d_in[6],  (const float*)d_in[11], (const float*)d_in[16]};
    const float* Wneigh[3] = {(const float*)d_in[7],  (const float*)d_in[12], (const float*)d_in[17]};
    const float* Adj   = (const float*)d_in[18];
    const float* noise = (const float*)d_in[19];
    const float* W1 = (const float*)d_in[20]; const float* b1 = (const float*)d_in[21];
    const float* W2 = (const float*)d_in[22]; const float* b2 = (const float*)d_in[23];
    const float* W3 = (const float*)d_in[24]; const float* b3 = (const float*)d_in[25];
    const float* W4 = (const float*)d_in[26]; const float* b4 = (const float*)d_in[27];
    const int* edges  = (const int*)d_in[28];
    const int* t_p    = (const int*)d_in[29];
    const int* left_p = (const int*)d_in[31];

    float* ws     = (float*)d_ws;
    float* pooled = ws;                                  // N*128
    float* agg    = pooled + (size_t)NNODE * FIN;        // N*128
    float* hA     = agg + (size_t)NNODE * FIN;           // 3*N*64
    float* hB     = hA + (size_t)NNODE * FOUT * 3;       // 3*N*64
    // MLP scratch aliases the (then dead) pooled+agg region:
    float* fakef = ws;
    float* x1 = ws + (size_t)SZ * FOUT;
    float* x2 = x1 + (size_t)SZ * 256;
    float* x3 = x2 + (size_t)SZ * 512;

    float* out_fake = (float*)d_out;
    float* out_x    = out_fake + (size_t)SZ * FOUT;

    const int SRCr[6] = {0, 1, 0, 2, 2, 1};
    const int DSTr[6] = {1, 0, 2, 0, 1, 2};

    dim3 blk(256);
    auto grid = [](int M, int Nn) { return dim3((Nn + 63) / 64, (M + 63) / 64); };

    // ---------- layer 1 (Fin=128 -> 64) ----------
    hipMemsetAsync(hA, 0, (size_t)NNODE * FOUT * 3 * sizeof(float), stream);
    for (int e = 0; e < 6; ++e) {
        int s = SRCr[e], d = DSTr[e];
        gemm_k<0, 1, 0, 0, 1><<<grid(NNODE, FIN), blk, 0, stream>>>(
            h0[s], nullptr, Wpool[0] + (size_t)e * FIN * FIN, bpool[0] + (size_t)e * FIN,
            pooled, NNODE, FIN, FIN);
        hipMemsetAsync(agg, 0, (size_t)NNODE * FIN * sizeof(float), stream);
        scatter_max_k<FIN><<<(NEDGE * (FIN / 4) + 255) / 256, blk, 0, stream>>>(
            pooled, edges + (size_t)e * 2 * NEDGE, edges + (size_t)e * 2 * NEDGE + NEDGE, agg);
        gemm_k<0, 0, 0, 1, 1><<<grid(NNODE, FOUT), blk, 0, stream>>>(
            h0[d], nullptr, Wself[0] + (size_t)e * FIN * FOUT, bself[0] + (size_t)e * FOUT,
            hA + (size_t)d * NNODE * FOUT, NNODE, FOUT, FIN);
        gemm_k<0, 0, 0, 1, 0><<<grid(NNODE, FOUT), blk, 0, stream>>>(
            agg, nullptr, Wneigh[0] + (size_t)e * FIN * FOUT, nullptr,
            hA + (size_t)d * NNODE * FOUT, NNODE, FOUT, FIN);
    }

    // ---------- layers 2,3 (64 -> 64) ----------
    float* hin = hA;
    float* hout = hB;
    for (int layer = 1; layer <= 2; ++layer) {
        hipMemsetAsync(hout, 0, (size_t)NNODE * FOUT * 3 * sizeof(float), stream);
        for (int e = 0; e < 6; ++e) {
            int s = SRCr[e], d = DSTr[e];
            gemm_k<0, 1, 0, 0, 1><<<grid(NNODE, HID), blk, 0, stream>>>(
                hin + (size_t)s * NNODE * HID, nullptr,
                Wpool[layer] + (size_t)e * HID * HID, bpool[layer] + (size_t)e * HID,
                pooled, NNODE, HID, HID);
            hipMemsetAsync(agg, 0, (size_t)NNODE * HID * sizeof(float), stream);
            scatter_max_k<HID><<<(NEDGE * (HID / 4) + 255) / 256, blk, 0, stream>>>(
                pooled, edges + (size_t)e * 2 * NEDGE, edges + (size_t)e * 2 * NEDGE + NEDGE, agg);
            gemm_k<0, 0, 0, 1, 1><<<grid(NNODE, FOUT), blk, 0, stream>>>(
                hin + (size_t)d * NNODE * HID, nullptr,
                Wself[layer] + (size_t)e * HID * FOUT, bself[layer] + (size_t)e * FOUT,
                hout + (size_t)d * NNODE * FOUT, NNODE, FOUT, HID);
            gemm_k<0, 0, 0, 1, 0><<<grid(NNODE, FOUT), blk, 0, stream>>>(
                agg, nullptr, Wneigh[layer] + (size_t)e * HID * FOUT, nullptr,
                hout + (size_t)d * NNODE * FOUT, NNODE, FOUT, HID);
        }
        float* tmp = hin; hin = hout; hout = tmp;
    }
    // hin == hA holds h3; mirna = hin + 0

    fake_k<<<SZ, dim3(64), 0, stream>>>(hin, noise, t_p, left_p, fakef, out_fake);

    // ---------- MLP ----------
    gemm_k<1, 1, 0, 0, 1><<<grid(SZ, 256), blk, 0, stream>>>(
        fakef, Adj, W1, b1, x1, SZ, 256, NITEMS + FOUT);
    gemm_k<0, 1, 0, 0, 1><<<grid(SZ, 512), blk, 0, stream>>>(
        x1, nullptr, W2, b2, x2, SZ, 512, 256);
    gemm_k<0, 1, 0, 0, 1><<<grid(SZ, 1024), blk, 0, stream>>>(
        x2, nullptr, W3, b3, x3, SZ, 1024, 512);
    gemm_k<0, 0, 1, 0, 1><<<grid(SZ, NITEMS), blk, 0, stream>>>(
        x3, nullptr, W4, b4, out_x, SZ, NITEMS, 1024);
}